// Round 1
// baseline (587.041 us; speedup 1.0000x reference)
//
#include <hip/hip_runtime.h>
#include <math.h>

#define H 8
#define DH 64
#define T 2048
#define D 512
#define B 2
#define MAXREL 32
#define NREL (2*MAXREL+1)
#define SCALE 0.125f   /* 64^-0.5 */

// ---------------------------------------------------------------------------
// Kernel 1: QKV projection.  C = X @ W + b for W in {Wq,Wk,Wv} (blockIdx.z).
// X: (4096, 512) row-major.  W: (512, 512) row-major.  Output written
// transposed per-head: dst[((b*H+h)*T + t)*DH + d]  (b,t from row; h,d from col)
// 64x64 tile per block, 256 threads, 4x4 per thread, fp32.
// ---------------------------------------------------------------------------
__global__ __launch_bounds__(256) void qkv_proj(
    const float* __restrict__ X,
    const float* __restrict__ Wq, const float* __restrict__ bq,
    const float* __restrict__ Wk, const float* __restrict__ bk,
    const float* __restrict__ Wv, const float* __restrict__ bv,
    float* __restrict__ Qo, float* __restrict__ Ko, float* __restrict__ Vo)
{
    const int which = blockIdx.z;
    const float* __restrict__ W    = (which == 0) ? Wq : (which == 1) ? Wk : Wv;
    const float* __restrict__ bias = (which == 0) ? bq : (which == 1) ? bk : bv;
    float* __restrict__ dst        = (which == 0) ? Qo : (which == 1) ? Ko : Vo;

    __shared__ __align__(16) float sA[16][64];   // [k][m]
    __shared__ __align__(16) float sB[16][64];   // [k][n]

    const int tid = threadIdx.x;
    const int m0 = blockIdx.x * 64;
    const int n0 = blockIdx.y * 64;
    const int tx = tid & 15;        // col group
    const int ty = tid >> 4;        // row group
    float acc[4][4] = {};

    for (int k0 = 0; k0 < D; k0 += 16) {
        // A tile: 64 rows x 16 k.  thread: row = tid>>2, k4 = (tid&3)*4
        {
            const int row = tid >> 2;
            const int k4  = (tid & 3) * 4;
            const float4 v = *(const float4*)&X[(m0 + row) * D + k0 + k4];
            sA[k4 + 0][row] = v.x; sA[k4 + 1][row] = v.y;
            sA[k4 + 2][row] = v.z; sA[k4 + 3][row] = v.w;
        }
        // B tile: 16 k rows x 64 n.  thread: kr = tid>>4, c4 = (tid&15)*4
        {
            const int kr = tid >> 4;
            const int c4 = (tid & 15) * 4;
            *(float4*)&sB[kr][c4] = *(const float4*)&W[(k0 + kr) * D + n0 + c4];
        }
        __syncthreads();
        #pragma unroll
        for (int kk = 0; kk < 16; ++kk) {
            const float4 a = *(const float4*)&sA[kk][ty * 4];
            const float4 b = *(const float4*)&sB[kk][tx * 4];
            const float av[4] = {a.x, a.y, a.z, a.w};
            const float bw[4] = {b.x, b.y, b.z, b.w};
            #pragma unroll
            for (int i = 0; i < 4; ++i)
                #pragma unroll
                for (int j = 0; j < 4; ++j)
                    acc[i][j] += av[i] * bw[j];
        }
        __syncthreads();
    }

    #pragma unroll
    for (int i = 0; i < 4; ++i) {
        const int m  = m0 + ty * 4 + i;
        const int bb = m / T;
        const int t  = m % T;
        #pragma unroll
        for (int j = 0; j < 4; ++j) {
            const int c = n0 + tx * 4 + j;
            const int h = c >> 6;
            const int d = c & 63;
            dst[((bb * H + h) * T + t) * DH + d] = acc[i][j] + bias[c];
        }
    }
}

// ---------------------------------------------------------------------------
// Kernel 2: flash-style attention, fp32.  One block per (q-tile=64, h, b).
// Q/K/V layout: [B][H][T][DH].  Output AO: [B*T][H*DH] row-major.
// 256 threads; thread (ty=tid>>4, tx=tid&15) owns rows 4*ty..+3, cols 4*tx..+3
// of each 64x64 tile (S-tile: cols = key idx; O-tile: cols = head dim).
// ---------------------------------------------------------------------------
__global__ __launch_bounds__(256) void attn_fwd(
    const float* __restrict__ Q, const float* __restrict__ K,
    const float* __restrict__ V, const float* __restrict__ relb,
    float* __restrict__ AO)
{
    const int qb = blockIdx.x * 64;
    const int h  = blockIdx.y;
    const int b  = blockIdx.z;
    const float* __restrict__ Qp = Q + (size_t)(b * H + h) * T * DH;
    const float* __restrict__ Kp = K + (size_t)(b * H + h) * T * DH;
    const float* __restrict__ Vp = V + (size_t)(b * H + h) * T * DH;

    __shared__ float Qs[64][65];
    __shared__ float Ks[64][65];
    __shared__ float Vs[64][65];
    __shared__ float Ps[64][65];
    __shared__ float rb[NREL];

    const int tid = threadIdx.x;
    const int tx = tid & 15;
    const int ty = tid >> 4;
    const int r0 = ty * 4;   // rows owned (q index within tile)
    const int c0 = tx * 4;   // cols owned

    if (tid < NREL) rb[tid] = relb[h * NREL + tid];

    // Load Q tile (64x64): row = tid>>2, 4 float4 per thread
    {
        const int r = tid >> 2;
        const float4* src = (const float4*)(Qp + (size_t)(qb + r) * DH) + (tid & 3) * 4;
        #pragma unroll
        for (int j = 0; j < 4; ++j) {
            const float4 v = src[j];
            const int c = (tid & 3) * 16 + j * 4;
            Qs[r][c] = v.x; Qs[r][c + 1] = v.y; Qs[r][c + 2] = v.z; Qs[r][c + 3] = v.w;
        }
    }

    float m[4], l[4], o[4][4];
    #pragma unroll
    for (int i = 0; i < 4; ++i) {
        m[i] = -INFINITY; l[i] = 0.f;
        #pragma unroll
        for (int j = 0; j < 4; ++j) o[i][j] = 0.f;
    }

    for (int kb = 0; kb < T; kb += 64) {
        __syncthreads();   // previous PV done; safe to overwrite K/V tiles
        // Load K,V tiles (row-major [key][d])
        {
            const int r = tid >> 2;
            const float4* ks = (const float4*)(Kp + (size_t)(kb + r) * DH) + (tid & 3) * 4;
            const float4* vs = (const float4*)(Vp + (size_t)(kb + r) * DH) + (tid & 3) * 4;
            #pragma unroll
            for (int j = 0; j < 4; ++j) {
                const float4 kv = ks[j];
                const float4 vv = vs[j];
                const int c = (tid & 3) * 16 + j * 4;
                Ks[r][c] = kv.x; Ks[r][c + 1] = kv.y; Ks[r][c + 2] = kv.z; Ks[r][c + 3] = kv.w;
                Vs[r][c] = vv.x; Vs[r][c + 1] = vv.y; Vs[r][c + 2] = vv.z; Vs[r][c + 3] = vv.w;
            }
        }
        __syncthreads();

        // S = Q K^T * SCALE + bias  (4x4 per thread)
        float s[4][4] = {};
        #pragma unroll 8
        for (int d = 0; d < 64; ++d) {
            float av[4], bw[4];
            #pragma unroll
            for (int i = 0; i < 4; ++i) av[i] = Qs[r0 + i][d];
            #pragma unroll
            for (int j = 0; j < 4; ++j) bw[j] = Ks[c0 + j][d];
            #pragma unroll
            for (int i = 0; i < 4; ++i)
                #pragma unroll
                for (int j = 0; j < 4; ++j)
                    s[i][j] += av[i] * bw[j];
        }
        #pragma unroll
        for (int i = 0; i < 4; ++i) {
            const int qg = qb + r0 + i;
            #pragma unroll
            for (int j = 0; j < 4; ++j) {
                const int kg  = kb + c0 + j;
                int rel = qg - kg;
                rel = rel < -MAXREL ? -MAXREL : (rel > MAXREL ? MAXREL : rel);
                s[i][j] = s[i][j] * SCALE + rb[rel + MAXREL];
            }
        }

        // online softmax update
        float alpha[4];
        #pragma unroll
        for (int i = 0; i < 4; ++i) {
            float mt = fmaxf(fmaxf(s[i][0], s[i][1]), fmaxf(s[i][2], s[i][3]));
            // reduce across the 16 lanes sharing these rows
            mt = fmaxf(mt, __shfl_xor(mt, 1));
            mt = fmaxf(mt, __shfl_xor(mt, 2));
            mt = fmaxf(mt, __shfl_xor(mt, 4));
            mt = fmaxf(mt, __shfl_xor(mt, 8));
            const float mn = fmaxf(m[i], mt);
            alpha[i] = __expf(m[i] - mn);
            float rs = 0.f;
            #pragma unroll
            for (int j = 0; j < 4; ++j) {
                const float p = __expf(s[i][j] - mn);
                Ps[r0 + i][c0 + j] = p;
                rs += p;
            }
            rs += __shfl_xor(rs, 1);
            rs += __shfl_xor(rs, 2);
            rs += __shfl_xor(rs, 4);
            rs += __shfl_xor(rs, 8);
            l[i] = l[i] * alpha[i] + rs;
            m[i] = mn;
            #pragma unroll
            for (int j = 0; j < 4; ++j) o[i][j] *= alpha[i];
        }
        __syncthreads();   // Ps visible

        // O += P V   (4x4 per thread, cols = head dim)
        #pragma unroll 8
        for (int k = 0; k < 64; ++k) {
            float av[4], bw[4];
            #pragma unroll
            for (int i = 0; i < 4; ++i) av[i] = Ps[r0 + i][k];
            #pragma unroll
            for (int j = 0; j < 4; ++j) bw[j] = Vs[k][c0 + j];
            #pragma unroll
            for (int i = 0; i < 4; ++i)
                #pragma unroll
                for (int j = 0; j < 4; ++j)
                    o[i][j] += av[i] * bw[j];
        }
    }

    // write AO[(b*T + q)*512 + h*64 + d] = o / l
    #pragma unroll
    for (int i = 0; i < 4; ++i) {
        const float inv = 1.f / l[i];
        const int q = qb + r0 + i;
        #pragma unroll
        for (int j = 0; j < 4; ++j)
            AO[(size_t)(b * T + q) * (H * DH) + h * DH + c0 + j] = o[i][j] * inv;
    }
}

// ---------------------------------------------------------------------------
// Kernel 3: output projection.  out = AO @ Wo + bo, row-major (4096 x 512).
// ---------------------------------------------------------------------------
__global__ __launch_bounds__(256) void out_proj(
    const float* __restrict__ X, const float* __restrict__ W,
    const float* __restrict__ bias, float* __restrict__ out)
{
    __shared__ __align__(16) float sA[16][64];
    __shared__ __align__(16) float sB[16][64];

    const int tid = threadIdx.x;
    const int m0 = blockIdx.x * 64;
    const int n0 = blockIdx.y * 64;
    const int tx = tid & 15;
    const int ty = tid >> 4;
    float acc[4][4] = {};

    for (int k0 = 0; k0 < D; k0 += 16) {
        {
            const int row = tid >> 2;
            const int k4  = (tid & 3) * 4;
            const float4 v = *(const float4*)&X[(m0 + row) * D + k0 + k4];
            sA[k4 + 0][row] = v.x; sA[k4 + 1][row] = v.y;
            sA[k4 + 2][row] = v.z; sA[k4 + 3][row] = v.w;
        }
        {
            const int kr = tid >> 4;
            const int c4 = (tid & 15) * 4;
            *(float4*)&sB[kr][c4] = *(const float4*)&W[(k0 + kr) * D + n0 + c4];
        }
        __syncthreads();
        #pragma unroll
        for (int kk = 0; kk < 16; ++kk) {
            const float4 a = *(const float4*)&sA[kk][ty * 4];
            const float4 b = *(const float4*)&sB[kk][tx * 4];
            const float av[4] = {a.x, a.y, a.z, a.w};
            const float bw[4] = {b.x, b.y, b.z, b.w};
            #pragma unroll
            for (int i = 0; i < 4; ++i)
                #pragma unroll
                for (int j = 0; j < 4; ++j)
                    acc[i][j] += av[i] * bw[j];
        }
        __syncthreads();
    }

    #pragma unroll
    for (int i = 0; i < 4; ++i) {
        const int mrow = m0 + ty * 4 + i;
        #pragma unroll
        for (int j = 0; j < 4; ++j) {
            const int c = n0 + tx * 4 + j;
            out[(size_t)mrow * D + c] = acc[i][j] + bias[c];
        }
    }
}

extern "C" void kernel_launch(void* const* d_in, const int* in_sizes, int n_in,
                              void* d_out, int out_size, void* d_ws, size_t ws_size,
                              hipStream_t stream)
{
    const float* hs   = (const float*)d_in[0];
    const float* Wq   = (const float*)d_in[1];
    const float* bq   = (const float*)d_in[2];
    const float* Wk   = (const float*)d_in[3];
    const float* bk   = (const float*)d_in[4];
    const float* Wv   = (const float*)d_in[5];
    const float* bv   = (const float*)d_in[6];
    const float* Wo   = (const float*)d_in[7];
    const float* bo   = (const float*)d_in[8];
    const float* relb = (const float*)d_in[9];

    const size_t NQKV = (size_t)B * T * H * DH;   // 2097152 floats
    float* ws = (float*)d_ws;
    float* Qd = ws;
    float* Kd = ws + NQKV;
    float* Vd = ws + 2 * NQKV;
    float* AO = ws + 3 * NQKV;

    qkv_proj<<<dim3((B * T) / 64, (H * DH) / 64, 3), 256, 0, stream>>>(
        hs, Wq, bq, Wk, bk, Wv, bv, Qd, Kd, Vd);
    attn_fwd<<<dim3(T / 64, H, B), 256, 0, stream>>>(Qd, Kd, Vd, relb, AO);
    out_proj<<<dim3((B * T) / 64, D / 64), 256, 0, stream>>>(AO, Wo, bo, (float*)d_out);
}

// Round 2
// 152.150 us; speedup vs baseline: 3.8583x; 3.8583x over previous
//
#include <hip/hip_runtime.h>
#include <stdint.h>
#include <math.h>

#define H 8
#define DH 64
#define T 2048
#define D 512
#define B 2
#define BH 16
#define MAXREL 32
#define NREL (2*MAXREL+1)
#define C1 0.18033688f           /* 0.125 * log2(e) */
#define NKIT 16                   /* key tiles per split (1024/64) */

typedef _Float16 half_t;
typedef half_t half8 __attribute__((ext_vector_type(8)));
typedef float f32x4 __attribute__((ext_vector_type(4)));

typedef __attribute__((address_space(3))) unsigned int lds_uint;
typedef const __attribute__((address_space(1))) unsigned int glb_uint;

__device__ __forceinline__ void gl_lds16(const void* g, void* l) {
    // async global->LDS, 16B/lane, LDS dest = wave-uniform base + lane*16
    __builtin_amdgcn_global_load_lds((glb_uint*)g, (lds_uint*)l, 16, 0, 0);
}

__device__ __forceinline__ f32x4 zero4() { f32x4 z = {0.f, 0.f, 0.f, 0.f}; return z; }

// ---------------------------------------------------------------------------
// Convert X (B*T x D fp32) -> fp16, no transpose.
// ---------------------------------------------------------------------------
__global__ __launch_bounds__(256) void cvt_x(const float* __restrict__ X,
                                             half_t* __restrict__ Xh) {
    const int i = (blockIdx.x * 256 + threadIdx.x) * 8;
    const float4 a = *(const float4*)(X + i);
    const float4 b = *(const float4*)(X + i + 4);
    half8 o;
    o[0]=(half_t)a.x; o[1]=(half_t)a.y; o[2]=(half_t)a.z; o[3]=(half_t)a.w;
    o[4]=(half_t)b.x; o[5]=(half_t)b.y; o[6]=(half_t)b.z; o[7]=(half_t)b.w;
    *(half8*)(Xh + i) = o;
}

// ---------------------------------------------------------------------------
// Transpose + convert weights: W[k][n] fp32 (512x512) -> Wt[n][k] fp16.
// grid: (64 tiles of 64x64, 4 weights)
// ---------------------------------------------------------------------------
__global__ __launch_bounds__(256) void trans_w(
    const float* __restrict__ Wq, const float* __restrict__ Wk,
    const float* __restrict__ Wv, const float* __restrict__ Wo,
    half_t* __restrict__ Wts) {
    const int z = blockIdx.y;
    const float* __restrict__ W = (z==0)?Wq:(z==1)?Wk:(z==2)?Wv:Wo;
    half_t* __restrict__ out = Wts + (size_t)z * (D * D);

    __shared__ half_t Ld[64 * 72];
    const int tid = threadIdx.x;
    const int k0 = (blockIdx.x >> 3) * 64;
    const int n0 = (blockIdx.x & 7) * 64;
    const int r = tid >> 2, c16 = (tid & 3) * 16;

    const float* src = W + (size_t)(k0 + r) * D + n0 + c16;
    #pragma unroll
    for (int j = 0; j < 16; ++j) Ld[r * 72 + c16 + j] = (half_t)src[j];
    __syncthreads();
    half_t tmp[16];
    #pragma unroll
    for (int j = 0; j < 16; ++j) tmp[j] = Ld[(c16 + j) * 72 + r];  // W[k0+c16+j][n0+r]
    half8* dst = (half8*)(out + (size_t)(n0 + r) * D + k0 + c16);
    dst[0] = *(half8*)&tmp[0];
    dst[1] = *(half8*)&tmp[8];
}

// ---------------------------------------------------------------------------
// QKV GEMM fp16 MFMA: C = Xh(4096x512) @ W + b.  Tile 64(m) x 128(n), BK=32.
// Writes per-head layout dst[bh][t][64] fp16 (bias added in fp32).
// grid: (64, 4, 3)
// ---------------------------------------------------------------------------
__global__ __launch_bounds__(256) void gemm_qkv(
    const half_t* __restrict__ Xh, const half_t* __restrict__ Wts,
    const float* __restrict__ bq, const float* __restrict__ bk,
    const float* __restrict__ bv,
    half_t* __restrict__ Qh, half_t* __restrict__ Kh, half_t* __restrict__ Vh)
{
    __shared__ half_t As[64 * 32];
    __shared__ half_t Bs[128 * 32];
    const int tid = threadIdx.x, w = tid >> 6, lane = tid & 63;
    const int l15 = lane & 15, quad = lane >> 4;
    const int m0 = blockIdx.x * 64, n0 = blockIdx.y * 128, z = blockIdx.z;
    const half_t* __restrict__ Wt = Wts + (size_t)z * (D * D);
    const float* __restrict__ bias = (z==0)?bq:(z==1)?bk:bv;
    half_t* __restrict__ dst = (z==0)?Qh:(z==1)?Kh:Vh;

    f32x4 acc[4][2];
    #pragma unroll
    for (int ms = 0; ms < 4; ++ms) { acc[ms][0] = zero4(); acc[ms][1] = zero4(); }

    for (int k0 = 0; k0 < D; k0 += 32) {
        {   // stage A (4 instrs, 1/wave) + B (8 instrs, 2/wave)
            const int cid = w * 64 + lane;
            gl_lds16(Xh + (size_t)(m0 + (cid >> 2)) * D + k0 + (cid & 3) * 8,
                     As + (size_t)w * 512);
            #pragma unroll
            for (int s = 0; s < 2; ++s) {
                const int cid2 = (w * 2 + s) * 64 + lane;
                gl_lds16(Wt + (size_t)(n0 + (cid2 >> 2)) * D + k0 + (cid2 & 3) * 8,
                         Bs + (size_t)(w * 2 + s) * 512);
            }
        }
        __syncthreads();
        half8 bf[2];
        #pragma unroll
        for (int nt = 0; nt < 2; ++nt)
            bf[nt] = *(const half8*)&Bs[(w * 32 + nt * 16 + l15) * 32 + quad * 8];
        #pragma unroll
        for (int ms = 0; ms < 4; ++ms) {
            const half8 af = *(const half8*)&As[(ms * 16 + l15) * 32 + quad * 8];
            acc[ms][0] = __builtin_amdgcn_mfma_f32_16x16x32_f16(af, bf[0], acc[ms][0], 0, 0, 0);
            acc[ms][1] = __builtin_amdgcn_mfma_f32_16x16x32_f16(af, bf[1], acc[ms][1], 0, 0, 0);
        }
        __syncthreads();
    }

    float bvv[2];
    #pragma unroll
    for (int nt = 0; nt < 2; ++nt) bvv[nt] = bias[n0 + w * 32 + nt * 16 + l15];
    #pragma unroll
    for (int ms = 0; ms < 4; ++ms)
        #pragma unroll
        for (int nt = 0; nt < 2; ++nt)
            #pragma unroll
            for (int r = 0; r < 4; ++r) {
                const int mrow = m0 + ms * 16 + quad * 4 + r;
                const int n = n0 + w * 32 + nt * 16 + l15;
                const int bb = mrow >> 11, t = mrow & 2047, h = n >> 6, d = n & 63;
                dst[(((size_t)bb * H + h) * T + t) * DH + d] = (half_t)(acc[ms][nt][r] + bvv[nt]);
            }
}

// ---------------------------------------------------------------------------
// V transpose: Vh[bh][t][d] -> Vth[bh][d][t].  grid: (32 t-tiles, 16 bh)
// ---------------------------------------------------------------------------
__global__ __launch_bounds__(256) void v_trans(const half_t* __restrict__ Vh,
                                               half_t* __restrict__ Vth) {
    __shared__ half_t Ld[64 * 72];
    const int tid = threadIdx.x;
    const int t0 = blockIdx.x * 64, bh = blockIdx.y;
    const int r = tid >> 2, c16 = (tid & 3) * 16;
    const half8* src = (const half8*)(Vh + ((size_t)bh * T + t0 + r) * DH + c16);
    *(half8*)&Ld[r * 72 + c16] = src[0];
    *(half8*)&Ld[r * 72 + c16 + 8] = src[1];
    __syncthreads();
    half_t tmp[16];
    #pragma unroll
    for (int j = 0; j < 16; ++j) tmp[j] = Ld[(c16 + j) * 72 + r];  // V[t0+c16+j][r]
    half8* dst = (half8*)(Vth + ((size_t)bh * DH + r) * T + t0 + c16);
    dst[0] = *(half8*)&tmp[0];
    dst[1] = *(half8*)&tmp[8];
}

// ---------------------------------------------------------------------------
// Flash attention, fp16 MFMA, no-max softmax (S bounded), split-K = 2.
// Block: 128 q-rows, 4 waves x 32q.  Per 64-key tile: QK^T (16 mfma),
// exp2 softmax, P->LDS (C-layout -> A-layout), PV (16 mfma).
// Writes unnormalized O/64 (fp16) + rowsum l/64 (fp16).
// grid: (16 q-tiles, 16 bh, 2 splits)
// ---------------------------------------------------------------------------
__global__ __launch_bounds__(256) void attn_fwd(
    const half_t* __restrict__ Qh, const half_t* __restrict__ Kh,
    const half_t* __restrict__ Vth, const float* __restrict__ relb,
    half_t* __restrict__ Onum, half_t* __restrict__ lsum)
{
    __shared__ half_t Kt[2][4096];     // 64 keys x 64 d, 8-half chunks XOR-swizzled
    __shared__ half_t Vt[2][4096];     // 64 d x 64 keys, swizzled
    __shared__ half_t Pl[4][2304];     // per-wave 32 x 72, chunk-swizzled
    __shared__ float rb2[NREL];

    const int tid = threadIdx.x, w = tid >> 6, lane = tid & 63;
    const int l15 = lane & 15, quad = lane >> 4;
    const int q0 = blockIdx.x * 128;
    const int bh = blockIdx.y;
    const int split = blockIdx.z;
    const int kb0 = split * 1024;
    const int h = bh & 7;

    if (tid < NREL) rb2[tid] = relb[h * NREL + tid] * 1.44269504f;

    // Q fragments direct from global (A-layout: m=l15, k contiguous)
    half8 qf[2][2];
    const half_t* Qbase = Qh + ((size_t)bh * T + q0 + w * 32) * DH;
    #pragma unroll
    for (int ms = 0; ms < 2; ++ms)
        #pragma unroll
        for (int ks = 0; ks < 2; ++ks)
            qf[ms][ks] = *(const half8*)(Qbase + (ms * 16 + l15) * DH + ks * 32 + quad * 8);

    f32x4 of[2][4];
    float lp[2][4];
    #pragma unroll
    for (int ms = 0; ms < 2; ++ms)
        #pragma unroll
        for (int nt = 0; nt < 4; ++nt) of[ms][nt] = zero4();
    #pragma unroll
    for (int ms = 0; ms < 2; ++ms)
        #pragma unroll
        for (int r = 0; r < 4; ++r) lp[ms][r] = 0.f;

    // stage K/Vt tile kb into buf (2 K + 2 V instrs per wave)
    auto stage = [&](int buf, int kb) {
        #pragma unroll
        for (int s = 0; s < 2; ++s) {
            const int cid = (w * 2 + s) * 64 + lane;
            const int r = cid >> 3, cg = (cid & 7) ^ (r & 7);
            gl_lds16(Kh + ((size_t)bh * T + kb + r) * DH + cg * 8,
                     &Kt[buf][(w * 2 + s) * 512]);
            gl_lds16(Vth + ((size_t)bh * DH + r) * T + kb + cg * 8,
                     &Vt[buf][(w * 2 + s) * 512]);
        }
    };

    stage(0, kb0);
    __syncthreads();

    for (int it = 0; it < NKIT; ++it) {
        const int cur = it & 1;
        if (it + 1 < NKIT) stage(cur ^ 1, kb0 + (it + 1) * 64);
        const int kb = kb0 + it * 64;

        // S = Q K^T
        f32x4 sf[2][4];
        #pragma unroll
        for (int ms = 0; ms < 2; ++ms)
            #pragma unroll
            for (int nt = 0; nt < 4; ++nt) sf[ms][nt] = zero4();
        #pragma unroll
        for (int ks = 0; ks < 2; ++ks)
            #pragma unroll
            for (int nt = 0; nt < 4; ++nt) {
                const int row = nt * 16 + l15;
                const int c = ks * 4 + quad;
                const half8 kf = *(const half8*)&Kt[cur][row * 64 + ((c ^ (row & 7)) * 8)];
                sf[0][nt] = __builtin_amdgcn_mfma_f32_16x16x32_f16(qf[0][ks], kf, sf[0][nt], 0, 0, 0);
                sf[1][nt] = __builtin_amdgcn_mfma_f32_16x16x32_f16(qf[1][ks], kf, sf[1][nt], 0, 0, 0);
            }

        // softmax (exp2, no max) + P -> LDS (fp16, A-layout target)
        const bool uni_hi = (q0 - (kb + 63)) >= MAXREL;
        const bool uni_lo = ((q0 + 127) - kb) <= -MAXREL;
        if (uni_hi || uni_lo) {
            const float bu = uni_hi ? rb2[NREL - 1] : rb2[0];
            #pragma unroll
            for (int ms = 0; ms < 2; ++ms)
                #pragma unroll
                for (int nt = 0; nt < 4; ++nt)
                    #pragma unroll
                    for (int r = 0; r < 4; ++r) {
                        const float p = exp2f(fmaf(sf[ms][nt][r], C1, bu));
                        lp[ms][r] += p;
                        const int row = ms * 16 + quad * 4 + r;
                        const int col = nt * 16 + l15;
                        Pl[w][row * 72 + ((((col >> 3) ^ (row & 7)) * 8) | (col & 7))] = (half_t)p;
                    }
        } else {
            #pragma unroll
            for (int ms = 0; ms < 2; ++ms)
                #pragma unroll
                for (int nt = 0; nt < 4; ++nt)
                    #pragma unroll
                    for (int r = 0; r < 4; ++r) {
                        const int q = q0 + w * 32 + ms * 16 + quad * 4 + r;
                        const int kg = kb + nt * 16 + l15;
                        int rel = q - kg;
                        rel = rel < -MAXREL ? -MAXREL : (rel > MAXREL ? MAXREL : rel);
                        const float p = exp2f(fmaf(sf[ms][nt][r], C1, rb2[rel + MAXREL]));
                        lp[ms][r] += p;
                        const int row = ms * 16 + quad * 4 + r;
                        const int col = nt * 16 + l15;
                        Pl[w][row * 72 + ((((col >> 3) ^ (row & 7)) * 8) | (col & 7))] = (half_t)p;
                    }
        }

        // O += P V  (P via wave-private LDS round-trip)
        #pragma unroll
        for (int ks = 0; ks < 2; ++ks) {
            half8 pf[2];
            #pragma unroll
            for (int ms = 0; ms < 2; ++ms) {
                const int row = ms * 16 + l15;
                const int c = ks * 4 + quad;
                pf[ms] = *(const half8*)&Pl[w][row * 72 + ((c ^ (row & 7)) * 8)];
            }
            #pragma unroll
            for (int nt = 0; nt < 4; ++nt) {
                const int row = nt * 16 + l15;
                const int c = ks * 4 + quad;
                const half8 vf = *(const half8*)&Vt[cur][row * 64 + ((c ^ (row & 7)) * 8)];
                of[0][nt] = __builtin_amdgcn_mfma_f32_16x16x32_f16(pf[0], vf, of[0][nt], 0, 0, 0);
                of[1][nt] = __builtin_amdgcn_mfma_f32_16x16x32_f16(pf[1], vf, of[1][nt], 0, 0, 0);
            }
        }
        __syncthreads();   // done reading cur; prefetch drained
    }

    // write O/64 and l/64
    const size_t obase = ((size_t)(split * BH + bh) * T + q0 + w * 32);
    #pragma unroll
    for (int ms = 0; ms < 2; ++ms)
        #pragma unroll
        for (int nt = 0; nt < 4; ++nt)
            #pragma unroll
            for (int r = 0; r < 4; ++r)
                Onum[(obase + ms * 16 + quad * 4 + r) * DH + nt * 16 + l15] =
                    (half_t)(of[ms][nt][r] * 0.015625f);

    #pragma unroll
    for (int ms = 0; ms < 2; ++ms)
        #pragma unroll
        for (int r = 0; r < 4; ++r) {
            float v = lp[ms][r];
            v += __shfl_xor(v, 1); v += __shfl_xor(v, 2);
            v += __shfl_xor(v, 4); v += __shfl_xor(v, 8);
            if (l15 == 0)
                lsum[obase + ms * 16 + quad * 4 + r] = (half_t)(v * 0.015625f);
        }
}

// ---------------------------------------------------------------------------
// Combine splits: AOh[r][c] = (O0+O1)/(l0+l1), fp16.  grid: 1024x256
// ---------------------------------------------------------------------------
__global__ __launch_bounds__(256) void combine(
    const half_t* __restrict__ Onum, const half_t* __restrict__ lsum,
    half_t* __restrict__ AOh)
{
    const int i = blockIdx.x * 256 + threadIdx.x;   // 262144 = 4096*512/8
    const int r = i >> 6;
    const int c = (i & 63) * 8;
    const int b = r >> 11, t = r & 2047, h = c >> 6, d = c & 63;
    const int bh = b * H + h;
    const size_t o0 = ((size_t)bh * T + t) * DH + d;
    const size_t o1 = ((size_t)(BH + bh) * T + t) * DH + d;
    const half8 x0 = *(const half8*)(Onum + o0);
    const half8 x1 = *(const half8*)(Onum + o1);
    const float l = (float)lsum[(size_t)bh * T + t] + (float)lsum[(size_t)(BH + bh) * T + t];
    const float inv = 1.0f / l;
    half8 o;
    #pragma unroll
    for (int j = 0; j < 8; ++j) o[j] = (half_t)(((float)x0[j] + (float)x1[j]) * inv);
    *(half8*)(AOh + (size_t)r * D + c) = o;
}

// ---------------------------------------------------------------------------
// Output projection: out = AOh(4096x512 fp16) @ Wo + bo, fp32 out.
// Same structure as gemm_qkv.  grid: (64, 4)
// ---------------------------------------------------------------------------
__global__ __launch_bounds__(256) void gemm_out(
    const half_t* __restrict__ AOh, const half_t* __restrict__ Wot,
    const float* __restrict__ bo, float* __restrict__ out)
{
    __shared__ half_t As[64 * 32];
    __shared__ half_t Bs[128 * 32];
    const int tid = threadIdx.x, w = tid >> 6, lane = tid & 63;
    const int l15 = lane & 15, quad = lane >> 4;
    const int m0 = blockIdx.x * 64, n0 = blockIdx.y * 128;

    f32x4 acc[4][2];
    #pragma unroll
    for (int ms = 0; ms < 4; ++ms) { acc[ms][0] = zero4(); acc[ms][1] = zero4(); }

    for (int k0 = 0; k0 < D; k0 += 32) {
        {
            const int cid = w * 64 + lane;
            gl_lds16(AOh + (size_t)(m0 + (cid >> 2)) * D + k0 + (cid & 3) * 8,
                     As + (size_t)w * 512);
            #pragma unroll
            for (int s = 0; s < 2; ++s) {
                const int cid2 = (w * 2 + s) * 64 + lane;
                gl_lds16(Wot + (size_t)(n0 + (cid2 >> 2)) * D + k0 + (cid2 & 3) * 8,
                         Bs + (size_t)(w * 2 + s) * 512);
            }
        }
        __syncthreads();
        half8 bf[2];
        #pragma unroll
        for (int nt = 0; nt < 2; ++nt)
            bf[nt] = *(const half8*)&Bs[(w * 32 + nt * 16 + l15) * 32 + quad * 8];
        #pragma unroll
        for (int ms = 0; ms < 4; ++ms) {
            const half8 af = *(const half8*)&As[(ms * 16 + l15) * 32 + quad * 8];
            acc[ms][0] = __builtin_amdgcn_mfma_f32_16x16x32_f16(af, bf[0], acc[ms][0], 0, 0, 0);
            acc[ms][1] = __builtin_amdgcn_mfma_f32_16x16x32_f16(af, bf[1], acc[ms][1], 0, 0, 0);
        }
        __syncthreads();
    }

    float bvv[2];
    #pragma unroll
    for (int nt = 0; nt < 2; ++nt) bvv[nt] = bo[n0 + w * 32 + nt * 16 + l15];
    #pragma unroll
    for (int ms = 0; ms < 4; ++ms)
        #pragma unroll
        for (int nt = 0; nt < 2; ++nt)
            #pragma unroll
            for (int r = 0; r < 4; ++r) {
                const int mrow = m0 + ms * 16 + quad * 4 + r;
                const int n = n0 + w * 32 + nt * 16 + l15;
                out[(size_t)mrow * D + n] = acc[ms][nt][r] + bvv[nt];
            }
}

extern "C" void kernel_launch(void* const* d_in, const int* in_sizes, int n_in,
                              void* d_out, int out_size, void* d_ws, size_t ws_size,
                              hipStream_t stream)
{
    const float* hs   = (const float*)d_in[0];
    const float* Wq   = (const float*)d_in[1];
    const float* bq   = (const float*)d_in[2];
    const float* Wk   = (const float*)d_in[3];
    const float* bk   = (const float*)d_in[4];
    const float* Wv   = (const float*)d_in[5];
    const float* bv   = (const float*)d_in[6];
    const float* Wo   = (const float*)d_in[7];
    const float* bo   = (const float*)d_in[8];
    const float* relb = (const float*)d_in[9];

    // workspace layout (fp16 elements); total 31.6 MB (ws >= 33.5 MB per R1)
    const size_t NX = (size_t)B * T * D;          // 2,097,152
    const size_t NW = (size_t)D * D;              // 262,144
    half_t* wsh = (half_t*)d_ws;
    half_t* Xh  = wsh;
    half_t* Wts = Xh + NX;            // Wq^T, Wk^T, Wv^T (3*NW)
    half_t* Wot = Wts + 3 * NW;
    half_t* Qh  = Wot + NW;
    half_t* Kh  = Qh + NX;
    half_t* Vh  = Kh + NX;            // reused as AOh after v_trans
    half_t* Vth = Vh + NX;
    half_t* On  = Vth + NX;           // 2 splits
    half_t* Ls  = On + 2 * NX;
    half_t* AOh = Vh;

    cvt_x   <<<dim3(NX / (256 * 8)), 256, 0, stream>>>(hs, Xh);
    trans_w <<<dim3(64, 4), 256, 0, stream>>>(Wq, Wk, Wv, Wo, Wts);
    gemm_qkv<<<dim3(64, 4, 3), 256, 0, stream>>>(Xh, Wts, bq, bk, bv, Qh, Kh, Vh);
    v_trans <<<dim3(32, BH), 256, 0, stream>>>(Vh, Vth);
    attn_fwd<<<dim3(16, BH, 2), 256, 0, stream>>>(Qh, Kh, Vth, relb, On, Ls);
    combine <<<dim3(1024), 256, 0, stream>>>(On, Ls, AOh);
    gemm_out<<<dim3(64, 4), 256, 0, stream>>>(AOh, Wot, bo, (float*)d_out);
}

// Round 4
// 147.417 us; speedup vs baseline: 3.9822x; 1.0321x over previous
//
#include <hip/hip_runtime.h>
#include <stdint.h>
#include <math.h>

#define H 8
#define DH 64
#define T 2048
#define D 512
#define B 2
#define BH 16
#define MAXREL 32
#define NREL (2*MAXREL+1)
#define C1 0.18033688f           /* 0.125 * log2(e) */
#define NW (D*D)

typedef _Float16 half_t;
typedef half_t half8 __attribute__((ext_vector_type(8)));
typedef half_t half4 __attribute__((ext_vector_type(4)));
typedef float f32x4 __attribute__((ext_vector_type(4)));
typedef int int4v __attribute__((ext_vector_type(4)));

typedef __attribute__((address_space(3))) unsigned int lds_uint;
typedef const __attribute__((address_space(1))) unsigned int glb_uint;

__device__ __forceinline__ void gl_lds16(const void* g, void* l) {
    __builtin_amdgcn_global_load_lds((glb_uint*)g, (lds_uint*)l, 16, 0, 0);
}
__device__ __forceinline__ f32x4 zero4() { f32x4 z = {0.f,0.f,0.f,0.f}; return z; }
__device__ __forceinline__ int pkrtz(float a, float b) {
    return __builtin_bit_cast(int, __builtin_amdgcn_cvt_pkrtz(a, b));
}

// ---------------------------------------------------------------------------
// prep: blocks [0,1024): X fp32 -> fp16.  blocks [1024,1280): W^T fp16.
// Wts holds Wq^T, Wk^T, Wv^T, Wo^T (each [n][k] fp16).
// ---------------------------------------------------------------------------
__global__ __launch_bounds__(256) void prep(
    const float* __restrict__ X,
    const float* __restrict__ Wq, const float* __restrict__ Wk,
    const float* __restrict__ Wv, const float* __restrict__ Wo,
    half_t* __restrict__ Xh, half_t* __restrict__ Wts)
{
    __shared__ half_t Ld[64 * 72];
    const int bid = blockIdx.x;
    const int tid = threadIdx.x;
    if (bid < 1024) {
        const int i = (bid * 256 + tid) * 8;
        const float4 a = *(const float4*)(X + i);
        const float4 b = *(const float4*)(X + i + 4);
        half8 o;
        o[0]=(half_t)a.x; o[1]=(half_t)a.y; o[2]=(half_t)a.z; o[3]=(half_t)a.w;
        o[4]=(half_t)b.x; o[5]=(half_t)b.y; o[6]=(half_t)b.z; o[7]=(half_t)b.w;
        *(half8*)(Xh + i) = o;
    } else {
        const int id = bid - 1024;
        const int z = id >> 6;
        const int tile = id & 63;
        const float* __restrict__ W = (z==0)?Wq:(z==1)?Wk:(z==2)?Wv:Wo;
        half_t* __restrict__ out = Wts + (size_t)z * NW;
        const int k0 = (tile >> 3) * 64;
        const int n0 = (tile & 7) * 64;
        const int r = tid >> 2, c16 = (tid & 3) * 16;
        const float* src = W + (size_t)(k0 + r) * D + n0 + c16;
        #pragma unroll
        for (int j = 0; j < 16; ++j) Ld[r * 72 + c16 + j] = (half_t)src[j];
        __syncthreads();
        half_t tmp[16];
        #pragma unroll
        for (int j = 0; j < 16; ++j) tmp[j] = Ld[(c16 + j) * 72 + r];
        half8* dst = (half8*)(out + (size_t)(n0 + r) * D + k0 + c16);
        dst[0] = *(half8*)&tmp[0];
        dst[1] = *(half8*)&tmp[8];
    }
}

// ---------------------------------------------------------------------------
// QKV GEMM: C = Xh(4096x512) @ W + b.  64m x 128n, BK=64, dbuf staging,
// XOR(r&7)-swizzled 128B LDS rows.  z=0 Q [bh][t][d]; z=1 K [bh][t][d];
// z=2 V written TRANSPOSED [bh][d][t].  grid (64,4,3).
// ---------------------------------------------------------------------------
__global__ __launch_bounds__(256) void gemm_qkv(
    const half_t* __restrict__ Xh, const half_t* __restrict__ Wts,
    const float* __restrict__ bq, const float* __restrict__ bk,
    const float* __restrict__ bv,
    half_t* __restrict__ Qh, half_t* __restrict__ Kh, half_t* __restrict__ Vth)
{
    __shared__ half_t As[2][64 * 64];
    __shared__ half_t Bs[2][128 * 64];
    const int tid = threadIdx.x, w = tid >> 6, lane = tid & 63;
    const int l15 = lane & 15, quad = lane >> 4;
    const int m0 = blockIdx.x * 64, n0 = blockIdx.y * 128, z = blockIdx.z;
    const half_t* __restrict__ Wt = Wts + (size_t)z * NW;
    const float* __restrict__ bias = (z==0)?bq:(z==1)?bk:bv;

    auto stage = [&](int buf, int k0) {
        #pragma unroll
        for (int s = 0; s < 2; ++s) {
            const int cid = (w * 2 + s) * 64 + lane;
            const int r = cid >> 3, c = (cid & 7) ^ (r & 7);
            gl_lds16(Xh + (size_t)(m0 + r) * D + k0 + c * 8,
                     &As[buf][(w * 2 + s) * 512]);
        }
        #pragma unroll
        for (int s = 0; s < 4; ++s) {
            const int cid = (w * 4 + s) * 64 + lane;
            const int r = cid >> 3, c = (cid & 7) ^ (r & 7);
            gl_lds16(Wt + (size_t)(n0 + r) * D + k0 + c * 8,
                     &Bs[buf][(w * 4 + s) * 512]);
        }
    };

    f32x4 acc[4][2];
    #pragma unroll
    for (int ms = 0; ms < 4; ++ms) { acc[ms][0] = zero4(); acc[ms][1] = zero4(); }

    stage(0, 0);
    __syncthreads();
    for (int it = 0; it < 8; ++it) {
        const int cur = it & 1;
        if (it < 7) stage(cur ^ 1, (it + 1) * 64);
        const int swiz = l15 & 7;
        #pragma unroll
        for (int ks = 0; ks < 2; ++ks) {
            const int c = (ks * 4 + quad) ^ swiz;
            half8 bf[2];
            #pragma unroll
            for (int nt = 0; nt < 2; ++nt)
                bf[nt] = *(const half8*)&Bs[cur][(w * 32 + nt * 16 + l15) * 64 + c * 8];
            #pragma unroll
            for (int ms = 0; ms < 4; ++ms) {
                const half8 af = *(const half8*)&As[cur][(ms * 16 + l15) * 64 + c * 8];
                acc[ms][0] = __builtin_amdgcn_mfma_f32_16x16x32_f16(af, bf[0], acc[ms][0], 0, 0, 0);
                acc[ms][1] = __builtin_amdgcn_mfma_f32_16x16x32_f16(af, bf[1], acc[ms][1], 0, 0, 0);
            }
        }
        __syncthreads();
    }

    float bvv[2];
    #pragma unroll
    for (int nt = 0; nt < 2; ++nt) bvv[nt] = bias[n0 + w * 32 + nt * 16 + l15];

    if (z == 2) {
        // V transposed: Vth[((bb*H+h)*DH + d)*T + t], 4 t-contiguous per store
        #pragma unroll
        for (int ms = 0; ms < 4; ++ms) {
            const int mbase = m0 + ms * 16 + quad * 4;
            const int bb = mbase >> 11, t0 = mbase & 2047;
            #pragma unroll
            for (int nt = 0; nt < 2; ++nt) {
                const int n = n0 + w * 32 + nt * 16 + l15;
                const int hh = n >> 6, d = n & 63;
                half4 pk;
                #pragma unroll
                for (int r = 0; r < 4; ++r) pk[r] = (half_t)(acc[ms][nt][r] + bvv[nt]);
                *(half4*)(Vth + (((size_t)bb * H + hh) * DH + d) * T + t0) = pk;
            }
        }
    } else {
        half_t* __restrict__ dst = (z == 0) ? Qh : Kh;
        #pragma unroll
        for (int ms = 0; ms < 4; ++ms)
            #pragma unroll
            for (int nt = 0; nt < 2; ++nt)
                #pragma unroll
                for (int r = 0; r < 4; ++r) {
                    const int mrow = m0 + ms * 16 + quad * 4 + r;
                    const int n = n0 + w * 32 + nt * 16 + l15;
                    const int bb = mrow >> 11, t = mrow & 2047, hh = n >> 6, d = n & 63;
                    dst[(((size_t)bb * H + hh) * T + t) * DH + d] = (half_t)(acc[ms][nt][r] + bvv[nt]);
                }
    }
}

// ---------------------------------------------------------------------------
// Flash attention, S^T orientation.  Block = 64 q (4 waves x 16 q), grid
// (32, 16, 2 splits).  Per 64-key tile: S^T = K.Q^T (8 mfma), exp2 softmax,
// quad-shuffle transpose of P (no LDS round-trip), O^T += V^T.P^T (8 mfma).
// Writes unnormalized O/64 fp16 + rowsum l/64 fp16.
// ---------------------------------------------------------------------------
__global__ __launch_bounds__(256) void attn_fwd(
    const half_t* __restrict__ Qh, const half_t* __restrict__ Kh,
    const half_t* __restrict__ Vth, const float* __restrict__ relb,
    half_t* __restrict__ Onum, half_t* __restrict__ lsum)
{
    __shared__ half_t Kt[2][4096];   // [key][d], XOR(r&7) chunk swizzle
    __shared__ half_t Vt[2][4096];   // [d][key], same swizzle
    __shared__ float rb2[NREL];

    const int tid = threadIdx.x, w = tid >> 6, lane = tid & 63;
    const int l15 = lane & 15, quad = lane >> 4;
    const int q0 = blockIdx.x * 64;
    const int qw = q0 + w * 16;              // this wave's 16 q-rows
    const int bh = blockIdx.y;
    const int split = blockIdx.z;
    const int kb0 = split * 1024;
    const int h = bh & 7;

    if (tid < NREL) rb2[tid] = relb[h * NREL + tid] * 1.44269504f;

    // Q as B-operand: n=q=l15(+qw), k = ks*32 + quad*8 + j
    half8 qf[2];
    const half_t* Qbase = Qh + ((size_t)bh * T + qw) * DH;
    #pragma unroll
    for (int ks = 0; ks < 2; ++ks)
        qf[ks] = *(const half8*)(Qbase + l15 * DH + ks * 32 + quad * 8);

    f32x4 of[4];
    #pragma unroll
    for (int nt = 0; nt < 4; ++nt) of[nt] = zero4();
    float lp = 0.f;

    auto stage = [&](int buf, int kb) {
        #pragma unroll
        for (int s = 0; s < 2; ++s) {
            const int cid = (w * 2 + s) * 64 + lane;
            const int r = cid >> 3, cg = (cid & 7) ^ (r & 7);
            gl_lds16(Kh + ((size_t)bh * T + kb + r) * DH + cg * 8,
                     &Kt[buf][(w * 2 + s) * 512]);
            gl_lds16(Vth + ((size_t)bh * DH + r) * T + kb + cg * 8,
                     &Vt[buf][(w * 2 + s) * 512]);
        }
    };

    stage(0, kb0);
    __syncthreads();

    const int qg = qw + l15;
    const int swiz = l15 & 7;

    for (int it = 0; it < 16; ++it) {
        const int cur = it & 1;
        if (it + 1 < 16) stage(cur ^ 1, kb0 + (it + 1) * 64);
        const int kb = kb0 + it * 64;

        // S^T = K . Q^T : A = K-frag (m=key), B = Q-frag (n=q)
        f32x4 st[4];
        #pragma unroll
        for (int nt = 0; nt < 4; ++nt) st[nt] = zero4();
        #pragma unroll
        for (int ks = 0; ks < 2; ++ks) {
            const int c = (ks * 4 + quad) ^ swiz;
            #pragma unroll
            for (int nt = 0; nt < 4; ++nt) {
                const half8 kf = *(const half8*)&Kt[cur][(nt * 16 + l15) * 64 + c * 8];
                st[nt] = __builtin_amdgcn_mfma_f32_16x16x32_f16(kf, qf[ks], st[nt], 0, 0, 0);
            }
        }

        // softmax (exp2, no max — S bounded) ; pack P^T to fp16 dwords
        int pd[4][2];
        const bool uni_hi = (qw - (kb + 63)) >= MAXREL;
        const bool uni_lo = ((qw + 15) - kb) <= -MAXREL;
        if (uni_hi || uni_lo) {
            const float bu = uni_hi ? rb2[NREL - 1] : rb2[0];
            #pragma unroll
            for (int nt = 0; nt < 4; ++nt) {
                float p[4];
                #pragma unroll
                for (int r = 0; r < 4; ++r) p[r] = exp2f(fmaf(st[nt][r], C1, bu));
                lp += (p[0] + p[1]) + (p[2] + p[3]);
                pd[nt][0] = pkrtz(p[0], p[1]);
                pd[nt][1] = pkrtz(p[2], p[3]);
            }
        } else {
            #pragma unroll
            for (int nt = 0; nt < 4; ++nt) {
                float p[4];
                #pragma unroll
                for (int r = 0; r < 4; ++r) {
                    const int key = kb + nt * 16 + quad * 4 + r;
                    int rel = qg - key;
                    rel = rel < -MAXREL ? -MAXREL : (rel > MAXREL ? MAXREL : rel);
                    p[r] = exp2f(fmaf(st[nt][r], C1, rb2[rel + MAXREL]));
                }
                lp += (p[0] + p[1]) + (p[2] + p[3]);
                pd[nt][0] = pkrtz(p[0], p[1]);
                pd[nt][1] = pkrtz(p[2], p[3]);
            }
        }

        // O^T += V^T . P^T : quad-shuffle C-layout -> B-layout, then mfma
        #pragma unroll
        for (int ks = 0; ks < 2; ++ks) {
            int4v bd;
            #pragma unroll
            for (int d = 0; d < 4; ++d) {
                const int src = ((quad & 1) * 2 + (d >> 1)) * 16 + l15;
                const int va = __shfl(pd[2 * ks][d & 1], src);
                const int vb = __shfl(pd[2 * ks + 1][d & 1], src);
                bd[d] = (quad >> 1) ? vb : va;
            }
            const half8 pf = __builtin_bit_cast(half8, bd);
            const int c = (ks * 4 + quad) ^ swiz;
            #pragma unroll
            for (int nt = 0; nt < 4; ++nt) {
                const half8 vf = *(const half8*)&Vt[cur][(nt * 16 + l15) * 64 + c * 8];
                of[nt] = __builtin_amdgcn_mfma_f32_16x16x32_f16(vf, pf, of[nt], 0, 0, 0);
            }
        }
        __syncthreads();
    }

    // epilogue: lane holds O^T for q = qw + l15, d = nt*16 + quad*4 + r
    const size_t qrow = (size_t)(split * BH + bh) * T + qw + l15;
    half_t* obase = Onum + qrow * DH;
    #pragma unroll
    for (int nt = 0; nt < 4; ++nt) {
        half4 pk;
        #pragma unroll
        for (int r = 0; r < 4; ++r) pk[r] = (half_t)(of[nt][r] * 0.015625f);
        *(half4*)(obase + nt * 16 + quad * 4) = pk;
    }
    lp += __shfl_xor(lp, 16);
    lp += __shfl_xor(lp, 32);
    if (quad == 0) lsum[qrow] = (half_t)(lp * 0.015625f);
}

// ---------------------------------------------------------------------------
// Combine splits: AOh[t][h*64+d] = (O0+O1)/(l0+l1), fp16.  grid 1024x256.
// ---------------------------------------------------------------------------
__global__ __launch_bounds__(256) void combine(
    const half_t* __restrict__ Onum, const half_t* __restrict__ lsum,
    half_t* __restrict__ AOh)
{
    const int i = blockIdx.x * 256 + threadIdx.x;
    const int r = i >> 6;
    const int c = (i & 63) * 8;
    const int b = r >> 11, t = r & 2047, hh = c >> 6, d = c & 63;
    const int bh = b * H + hh;
    const size_t o0 = ((size_t)bh * T + t) * DH + d;
    const size_t o1 = ((size_t)(BH + bh) * T + t) * DH + d;
    const half8 x0 = *(const half8*)(Onum + o0);
    const half8 x1 = *(const half8*)(Onum + o1);
    const float l = (float)lsum[(size_t)bh * T + t] + (float)lsum[(size_t)(BH + bh) * T + t];
    const float inv = 1.0f / l;
    half8 o;
    #pragma unroll
    for (int j = 0; j < 8; ++j) o[j] = (half_t)(((float)x0[j] + (float)x1[j]) * inv);
    *(half8*)(AOh + (size_t)r * D + c) = o;
}

// ---------------------------------------------------------------------------
// Output projection: out = AOh(4096x512) @ Wo + bo, fp32 out.
// 32m x 128n, BK=64, dbuf, swizzled.  grid (128, 4).
// ---------------------------------------------------------------------------
__global__ __launch_bounds__(256) void gemm_out(
    const half_t* __restrict__ AOh, const half_t* __restrict__ Wot,
    const float* __restrict__ bo, float* __restrict__ out)
{
    __shared__ half_t As[2][32 * 64];
    __shared__ half_t Bs[2][128 * 64];
    const int tid = threadIdx.x, w = tid >> 6, lane = tid & 63;
    const int l15 = lane & 15, quad = lane >> 4;
    const int m0 = blockIdx.x * 32, n0 = blockIdx.y * 128;

    auto stage = [&](int buf, int k0) {
        {
            const int cid = w * 64 + lane;
            const int r = cid >> 3, c = (cid & 7) ^ (r & 7);
            gl_lds16(AOh + (size_t)(m0 + r) * D + k0 + c * 8,
                     &As[buf][w * 512]);
        }
        #pragma unroll
        for (int s = 0; s < 4; ++s) {
            const int cid = (w * 4 + s) * 64 + lane;
            const int r = cid >> 3, c = (cid & 7) ^ (r & 7);
            gl_lds16(Wot + (size_t)(n0 + r) * D + k0 + c * 8,
                     &Bs[buf][(w * 4 + s) * 512]);
        }
    };

    f32x4 acc[2][2];
    #pragma unroll
    for (int ms = 0; ms < 2; ++ms) { acc[ms][0] = zero4(); acc[ms][1] = zero4(); }

    stage(0, 0);
    __syncthreads();
    for (int it = 0; it < 8; ++it) {
        const int cur = it & 1;
        if (it < 7) stage(cur ^ 1, (it + 1) * 64);
        const int swiz = l15 & 7;
        #pragma unroll
        for (int ks = 0; ks < 2; ++ks) {
            const int c = (ks * 4 + quad) ^ swiz;
            half8 bf[2];
            #pragma unroll
            for (int nt = 0; nt < 2; ++nt)
                bf[nt] = *(const half8*)&Bs[cur][(w * 32 + nt * 16 + l15) * 64 + c * 8];
            #pragma unroll
            for (int ms = 0; ms < 2; ++ms) {
                const half8 af = *(const half8*)&As[cur][(ms * 16 + l15) * 64 + c * 8];
                acc[ms][0] = __builtin_amdgcn_mfma_f32_16x16x32_f16(af, bf[0], acc[ms][0], 0, 0, 0);
                acc[ms][1] = __builtin_amdgcn_mfma_f32_16x16x32_f16(af, bf[1], acc[ms][1], 0, 0, 0);
            }
        }
        __syncthreads();
    }

    float bvv[2];
    #pragma unroll
    for (int nt = 0; nt < 2; ++nt) bvv[nt] = bo[n0 + w * 32 + nt * 16 + l15];
    #pragma unroll
    for (int ms = 0; ms < 2; ++ms)
        #pragma unroll
        for (int nt = 0; nt < 2; ++nt)
            #pragma unroll
            for (int r = 0; r < 4; ++r) {
                const int mrow = m0 + ms * 16 + quad * 4 + r;
                const int n = n0 + w * 32 + nt * 16 + l15;
                out[(size_t)mrow * D + n] = acc[ms][nt][r] + bvv[nt];
            }
}

extern "C" void kernel_launch(void* const* d_in, const int* in_sizes, int n_in,
                              void* d_out, int out_size, void* d_ws, size_t ws_size,
                              hipStream_t stream)
{
    const float* hs   = (const float*)d_in[0];
    const float* Wq   = (const float*)d_in[1];
    const float* bq   = (const float*)d_in[2];
    const float* Wk   = (const float*)d_in[3];
    const float* bk   = (const float*)d_in[4];
    const float* Wv   = (const float*)d_in[5];
    const float* bv   = (const float*)d_in[6];
    const float* Wo   = (const float*)d_in[7];
    const float* bo   = (const float*)d_in[8];
    const float* relb = (const float*)d_in[9];

    // workspace (fp16 elements), total ~30.1 MB
    const size_t NX = (size_t)B * T * D;          // 2,097,152
    half_t* wsh = (half_t*)d_ws;
    half_t* Xh  = wsh;
    half_t* Wts = Xh + NX;            // Wq^T,Wk^T,Wv^T,Wo^T (4*NW)
    half_t* Qh  = Wts + 4 * (size_t)NW;
    half_t* Kh  = Qh + NX;
    half_t* Vth = Kh + NX;
    half_t* On  = Vth + NX;           // 2 splits
    half_t* Ls  = On + 2 * NX;        // 2*BH*T
    half_t* AOh = Ls + 2 * BH * T;

    prep    <<<dim3(1280), 256, 0, stream>>>(hs, Wq, Wk, Wv, Wo, Xh, Wts);
    gemm_qkv<<<dim3(64, 4, 3), 256, 0, stream>>>(Xh, Wts, bq, bk, bv, Qh, Kh, Vth);
    attn_fwd<<<dim3(32, BH, 2), 256, 0, stream>>>(Qh, Kh, Vth, relb, On, Ls);
    combine <<<dim3(1024), 256, 0, stream>>>(On, Ls, AOh);
    gemm_out<<<dim3(128, 4), 256, 0, stream>>>(AOh, Wts + 3 * (size_t)NW, bo, (float*)d_out);
}